// Round 14
// baseline (114.948 us; speedup 1.0000x reference)
//
#include <hip/hip_runtime.h>
#include <hip/hip_bf16.h>

typedef __attribute__((ext_vector_type(4))) float  floatx4;
typedef __attribute__((ext_vector_type(2))) float  floatx2;
typedef __attribute__((ext_vector_type(8))) __bf16 bf16x8;

#define FP8_MAX 448.0f

// HW OCP e4m3fn round-trip (RNE), matches ml_dtypes float8_e4m3fn for |v|<=448
__device__ __forceinline__ floatx2 fp8_qdq2(float a, float b) {
    int p = __builtin_amdgcn_cvt_pk_fp8_f32(a, b, 0, false);
    return __builtin_amdgcn_cvt_pk_f32_fp8(p, false);
}

__device__ __forceinline__ unsigned int f2bf(float f) {
    union { __hip_bfloat16 h; unsigned short u; } cv;
    cv.h = __float2bfloat16(f);
    return (unsigned int)cv.u;
}

__device__ __forceinline__ void async_copy16(void* lds, const void* g) {
    __builtin_amdgcn_global_load_lds(
        (const __attribute__((address_space(1))) unsigned int*)g,
        (__attribute__((address_space(3))) unsigned int*)lds, 16, 0, 0);
}

// ---------------------------------------------------------------------------
// Kernel 1: dequantize W [D=512][F=512] (quant blocks of 128 along F),
//           write transposed bf16 Wt [F=512][D=512].
__global__ void wdq_kernel(const float* __restrict__ W,
                           __hip_bfloat16* __restrict__ Wt) {
    const int D = 512, F = 512;
    int d = blockIdx.x;
    int t = threadIdx.x;
    float4 v = *reinterpret_cast<const float4*>(W + (size_t)d * F + t * 4);
    float am = fmaxf(fmaxf(fabsf(v.x), fabsf(v.y)), fmaxf(fabsf(v.z), fabsf(v.w)));
#pragma unroll
    for (int s = 16; s >= 1; s >>= 1) am = fmaxf(am, __shfl_xor(am, s));
    float scale = fmaxf(am, 1e-4f) / FP8_MAX;
    floatx2 d01 = fp8_qdq2(v.x / scale, v.y / scale);
    floatx2 d23 = fp8_qdq2(v.z / scale, v.w / scale);
    int f0 = t * 4;
    Wt[(size_t)(f0 + 0) * D + d] = __float2bfloat16(d01[0] * scale);
    Wt[(size_t)(f0 + 1) * D + d] = __float2bfloat16(d01[1] * scale);
    Wt[(size_t)(f0 + 2) * D + d] = __float2bfloat16(d23[0] * scale);
    Wt[(size_t)(f0 + 3) * D + d] = __float2bfloat16(d23[1] * scale);
}

// ---------------------------------------------------------------------------
// Kernel 2 (fused): ROUND-4 STRUCTURE (plain __syncthreads every K-step --
// race-impossible by construction: every barrier drains vmcnt(0)), tile
// shrunk to BM=64/BN=128 so LDS = As 16K + Bs 32K = 48 KB -> 3 blocks/CU.
// The 3 resident blocks run at independent pipeline phases and fill each
// other's barrier drains (m97/m114 TLP mechanism) -- this is the
// good-structure x high-TLP cell rounds 3-13 never safely tested.
// 256 thr = 4 waves (2M x 2N), wave tile 32x64, acc[2][4] = 16 MFMA/step.
// Single X stash (v) + q4 regs: ~130 VGPR, safely under the 170 cap of
// __launch_bounds__(256,3) -> no scratch (R13 lesson: spills + counted
// vmcnt = race; here there are no counted waits at all).
// X quant blocks of 128 span two K-steps; loads issued ~1.5 steps ahead
// (latency overlapped with the barrier drain that happens regardless).
// XOR slot swizzle both-sides (slot ^= row&7): 0 conflicts (rounds 3-12).
__global__ __launch_bounds__(256, 3) void fused_gemm(
        const float* __restrict__ X,             // [M][512] f32
        const __hip_bfloat16* __restrict__ Wt,   // [512 f][512 k] bf16
        const float* __restrict__ bias,          // [512]
        float* __restrict__ C, int M) {
    const int K = 512, N = 512;
    __shared__ char As[2][8192];    // [64 r][8 slot16B], swizzled
    __shared__ char Bs[2][16384];   // [128 f][8 slot16B], swizzled

    // XCD-chunked bijective swizzle (grid 4096 % 8 == 0): the 4 tN tiles of
    // each tM adjacent on one XCD -> X fetched from HBM once, re-read from L2.
    int bx   = blockIdx.x;
    int tile = (bx & 7) * (gridDim.x >> 3) + (bx >> 3);
    int tN   = tile & 3;             // N-panel of 128
    int tM   = tile >> 2;            // M-tile of 64 rows

    int tid = threadIdx.x, wid = tid >> 6, lane = tid & 63;
    int wm = wid >> 1, wn = wid & 1; // wave grid 2(M) x 2(N), tile 32x64
    int lr = lane & 15, lg = lane >> 4;
    int ar = tid >> 2, aq = tid & 3; // A-quant: 4 thr/row, 32 f32 each

    const float* Xb = X + (size_t)(tM * 64) * K;
    const char* Wb  = (const char*)(Wt + (size_t)tN * 128 * K);
    float* Cb = C + (size_t)(tM * 64) * N + tN * 128;

    float4 v[8];        // X stash (one 128-k quant block slice)
    uint4  q4[4];       // quantized bf16 (32 elems = 4 slots)
    floatx4 acc[2][4] = {};

    auto loadX = [&](int qb) {
        const float* src = Xb + (size_t)ar * K + qb * 128 + aq * 32;
#pragma unroll
        for (int j = 0; j < 8; ++j)
            v[j] = *reinterpret_cast<const float4*>(src + j * 4);
    };
    auto quantX = [&]() {
        float am = 0.f;
#pragma unroll
        for (int j = 0; j < 8; ++j)
            am = fmaxf(am, fmaxf(fmaxf(fabsf(v[j].x), fabsf(v[j].y)),
                                 fmaxf(fabsf(v[j].z), fabsf(v[j].w))));
        am = fmaxf(am, __shfl_xor(am, 1));
        am = fmaxf(am, __shfl_xor(am, 2));
        am = fmaxf(am, 1e-4f);
        float scale = am / FP8_MAX;     // exact reference scale (IEEE div)
        float inv   = FP8_MAX / am;
#pragma unroll
        for (int n = 0; n < 4; ++n) {
            floatx2 a0 = fp8_qdq2(v[2*n].x*inv,   v[2*n].y*inv);
            floatx2 a1 = fp8_qdq2(v[2*n].z*inv,   v[2*n].w*inv);
            floatx2 a2 = fp8_qdq2(v[2*n+1].x*inv, v[2*n+1].y*inv);
            floatx2 a3 = fp8_qdq2(v[2*n+1].z*inv, v[2*n+1].w*inv);
            q4[n].x = f2bf(a0[0]*scale) | (f2bf(a0[1]*scale) << 16);
            q4[n].y = f2bf(a1[0]*scale) | (f2bf(a1[1]*scale) << 16);
            q4[n].z = f2bf(a2[0]*scale) | (f2bf(a2[1]*scale) << 16);
            q4[n].w = f2bf(a3[0]*scale) | (f2bf(a3[1]*scale) << 16);
        }
    };
    auto writeA = [&](int buf, int hb) {   // k-half hb of q4 -> As[buf]
        if ((aq >> 1) == hb) {
#pragma unroll
            for (int n = 0; n < 4; ++n) {
                int slot = (aq & 1) * 4 + n;
                *reinterpret_cast<uint4*>(
                    As[buf] + ar * 128 + ((slot ^ (ar & 7)) << 4)) = q4[n];
            }
        }
    };
    auto stageB = [&](int buf, int step) {   // 16 x 1KB chunks, 4/wave
        const char* base = Wb + step * 128;
#pragma unroll
        for (int cc = 0; cc < 4; ++cc) {
            int c  = wid * 4 + cc;
            int rr = c * 8 + (lane >> 3);
            int d  = lane & 7;
            async_copy16(Bs[buf] + c * 1024,
                         base + (size_t)rr * (K * 2) + ((d ^ (rr & 7)) << 4));
        }
    };
    auto mfmaStep = [&](int buf) {
        __builtin_amdgcn_s_setprio(1);
#pragma unroll
        for (int ks = 0; ks < 2; ++ks) {
            int q = (ks << 2) | lg;
            bf16x8 a[2], b[4];
#pragma unroll
            for (int mi = 0; mi < 2; ++mi) {
                int r = wm * 32 + mi * 16 + lr;
                a[mi] = *reinterpret_cast<const bf16x8*>(
                    As[buf] + r * 128 + ((q ^ (r & 7)) << 4));
            }
#pragma unroll
            for (int ni = 0; ni < 4; ++ni) {
                int f = wn * 64 + ni * 16 + lr;
                b[ni] = *reinterpret_cast<const bf16x8*>(
                    Bs[buf] + f * 128 + ((q ^ (f & 7)) << 4));
            }
#pragma unroll
            for (int mi = 0; mi < 2; ++mi)
#pragma unroll
                for (int ni = 0; ni < 4; ++ni)
                    acc[mi][ni] = __builtin_amdgcn_mfma_f32_16x16x32_bf16(
                        a[mi], b[ni], acc[mi][ni], 0, 0, 0);
        }
        __builtin_amdgcn_s_setprio(0);
    };

    // ---- prologue: quant qb0, As[0]=half0, Bs[0]=step0, qb1 in flight ----
    loadX(0);
    stageB(0, 0);
    quantX();          // waits qb0 (B0 DMAs keep flowing)
    writeA(0, 0);
    loadX(1);
    __syncthreads();

    // ---- main: 8 K-steps, one __syncthreads each, full double-buffer -----
#pragma unroll
    for (int s = 0; s < 8; ++s) {
        int cur = s & 1, nxt = cur ^ 1;
        if (s < 7) stageB(nxt, s + 1);
        if ((s & 1) == 0) {
            if (s < 7) writeA(nxt, 1);               // half1 of current block
        } else if (s < 7) {
            quantX();                                // block (s+1)/2
            writeA(nxt, 0);                          // its half0
            if (s < 5) loadX((s + 3) / 2);           // next X, ~1.5 steps ahead
        }
        mfmaStep(cur);
        if (s < 7) __syncthreads();
    }

    // ---- epilogue: C/D layout col=lane&15, row=(lane>>4)*4+e --------------
#pragma unroll
    for (int ni = 0; ni < 4; ++ni) {
        int col = wn * 64 + ni * 16 + lr;
        float bv = bias[tN * 128 + col];
#pragma unroll
        for (int mi = 0; mi < 2; ++mi) {
            int r0 = wm * 32 + mi * 16 + lg * 4;
#pragma unroll
            for (int e = 0; e < 4; ++e)
                Cb[(size_t)(r0 + e) * N + col] = acc[mi][ni][e] + bv;
        }
    }
}

// ---------------------------------------------------------------------------
extern "C" void kernel_launch(void* const* d_in, const int* in_sizes, int n_in,
                              void* d_out, int out_size, void* d_ws, size_t ws_size,
                              hipStream_t stream) {
    const float* X    = (const float*)d_in[0];
    const float* W    = (const float*)d_in[1];
    const float* bias = (const float*)d_in[2];
    const int K = 512;
    const int M = in_sizes[0] / K;   // 65536

    __hip_bfloat16* Wt = (__hip_bfloat16*)d_ws;   // 512*512*2 = 512 KB

    wdq_kernel<<<dim3(512), dim3(128), 0, stream>>>(W, Wt);
    fused_gemm<<<dim3((M / 64) * (512 / 128)), dim3(256), 0, stream>>>(
        X, Wt, bias, (float*)d_out, M);
}